// Round 12
// baseline (255.912 us; speedup 1.0000x reference)
//
#include <hip/hip_runtime.h>
#include <math.h>

#define N_NODES 100000
#define CH 64
#define N_EDGES 1600000
#define N_PAIRS 200000

#define PB    196            // buckets of 512 dst nodes (196*512 = 100352)
#define PCAP  9216           // slots per bucket (mean 8163, ~11 sigma)

// Sliced feature layout: 4 slices x 16 channels (32B). buf4[(s*N + n)*2 + q]
// holds channels 16s+8q .. 16s+8q+8 of node n. Each gather block handles one
// slice; bid&3 -> slice, so round-robin bid->XCD gives each XCD ONE 3.2MB
// slice = L2-resident gather source.

typedef unsigned short ushort_t;
typedef unsigned int   uint_t;
typedef __attribute__((ext_vector_type(8))) short short8_t;   // 8 bf16
typedef __attribute__((ext_vector_type(4))) short short4_t;   // 4 bf16 = 8B
typedef __attribute__((ext_vector_type(4))) float f32x4;      // MFMA acc

// ---- bf16 helpers ----------------------------------------------------------
__device__ __forceinline__ float asf(uint_t u) {
    union { uint_t u; float f; } c; c.u = u; return c.f;
}
__device__ __forceinline__ uint_t f2bf(float f) {
    union { float f; uint_t u; } c; c.f = f;
    return (c.u + 0x7FFFu + ((c.u >> 16) & 1u)) >> 16;
}
__device__ __forceinline__ uint_t pack2(float lo, float hi) {
    return f2bf(lo) | (f2bf(hi) << 16);
}

// ---------------------------------------------------------------------------
// Pass A: bucket edges by dst>>9. Packed record: src<<9 | (dst & 511).
// ---------------------------------------------------------------------------
__global__ void k_bucketA(const int* __restrict__ src, const int* __restrict__ dst,
                          int* __restrict__ gcur, uint_t* __restrict__ rec) {
    __shared__ int hist[PB];
    __shared__ int cur[PB];
    int tid = threadIdx.x;              // 256
    if (tid < PB) hist[tid] = 0;
    __syncthreads();
    const int NQ = N_EDGES / 4;         // 400000 int4 quads
    int per = (NQ + gridDim.x - 1) / gridDim.x;
    int q0 = blockIdx.x * per;
    int q1 = min(q0 + per, NQ);
    const int4* dst4 = (const int4*)dst;
    const int4* src4 = (const int4*)src;
    for (int qd = q0 + tid; qd < q1; qd += 256) {
        int4 d = dst4[qd];
        atomicAdd(&hist[d.x >> 9], 1);
        atomicAdd(&hist[d.y >> 9], 1);
        atomicAdd(&hist[d.z >> 9], 1);
        atomicAdd(&hist[d.w >> 9], 1);
    }
    __syncthreads();
    if (tid < PB) cur[tid] = atomicAdd(&gcur[tid], hist[tid]);
    __syncthreads();
    for (int qd = q0 + tid; qd < q1; qd += 256) {
        int4 d = dst4[qd];
        int4 s = src4[qd];
        int b, pos;
        b = d.x >> 9; pos = atomicAdd(&cur[b], 1);
        rec[(size_t)b * PCAP + pos] = ((uint_t)s.x << 9) | (uint_t)(d.x & 511);
        b = d.y >> 9; pos = atomicAdd(&cur[b], 1);
        rec[(size_t)b * PCAP + pos] = ((uint_t)s.y << 9) | (uint_t)(d.y & 511);
        b = d.z >> 9; pos = atomicAdd(&cur[b], 1);
        rec[(size_t)b * PCAP + pos] = ((uint_t)s.z << 9) | (uint_t)(d.z & 511);
        b = d.w >> 9; pos = atomicAdd(&cur[b], 1);
        rec[(size_t)b * PCAP + pos] = ((uint_t)s.w << 9) | (uint_t)(d.w & 511);
    }
}

// ---------------------------------------------------------------------------
// Pass B (fused): per-bucket 512-bin counting sort -> row_start + sorted csr.
// ---------------------------------------------------------------------------
__global__ __launch_bounds__(256) void k_sortplace(const uint_t* __restrict__ rec,
                                                   const int* __restrict__ gcur,
                                                   int* __restrict__ row_start,
                                                   int* __restrict__ csr) {
    __shared__ uint_t ebuf[PCAP];       // 36 KB
    __shared__ int sc[256];
    __shared__ int hist[512];
    __shared__ int offx[512];
    __shared__ int cur[512];
    int b = blockIdx.x, tid = threadIdx.x;

    // bucket base = exclusive prefix of gcur
    sc[tid] = (tid < PB) ? gcur[tid] : 0;
    __syncthreads();
    for (int off = 1; off < 256; off <<= 1) {
        int v = (tid >= off) ? sc[tid - off] : 0;
        __syncthreads();
        sc[tid] += v;
        __syncthreads();
    }
    int base = (b == 0) ? 0 : sc[b - 1];
    int len  = gcur[b];
    __syncthreads();

    // stage + 512-bin histogram
    for (int i = tid; i < 512; i += 256) hist[i] = 0;
    __syncthreads();
    const uint_t* r = rec + (size_t)b * PCAP;
    for (int e = tid; e < len; e += 256) {
        uint_t pk = r[e];
        ebuf[e] = pk;
        atomicAdd(&hist[pk & 511u], 1);
    }
    __syncthreads();

    // exclusive scan of 512 bins
    int p0 = hist[2 * tid], p1 = hist[2 * tid + 1];
    sc[tid] = p0 + p1;
    __syncthreads();
    for (int off = 1; off < 256; off <<= 1) {
        int v = (tid >= off) ? sc[tid - off] : 0;
        __syncthreads();
        sc[tid] += v;
        __syncthreads();
    }
    int exclp = sc[tid] - (p0 + p1);
    offx[2 * tid] = exclp;
    offx[2 * tid + 1] = exclp + p0;
    cur[2 * tid] = exclp;
    cur[2 * tid + 1] = exclp + p0;
    __syncthreads();

    // row_start
    int n0 = b * 512;
    for (int j = tid; j < 512; j += 256) {
        int gn = n0 + j;
        if (gn < N_NODES) row_start[gn] = base + offx[j];
    }
    if (b == PB - 1 && tid == 0) row_start[N_NODES] = N_EDGES;

    // scatter sorted
    for (int e = tid; e < len; e += 256) {
        uint_t pk = ebuf[e];
        int pos = atomicAdd(&cur[pk & 511u], 1);
        csr[base + pos] = (int)(pk >> 9);
    }
}

// ---------------------------------------------------------------------------
// MFMA dual GEMM: outa = in@Wa ; outb = in@Wb + bias  (fp32 acc, bf16 out).
// SLICED=false: row-major fp32 input (layer 1's x). SLICED=true: slice-major
// bf16 input. Output is ALWAYS slice-major. Each wave owns rows n%16==r16:
// all b-frag loads retire into regs before any store (lockstep) -> in-place ok.
// ---------------------------------------------------------------------------
__device__ __forceinline__ short8_t bfrag_f32(const float* in, size_t off) {
    float4 f0 = ((const float4*)(in + off))[0];
    float4 f1 = ((const float4*)(in + off))[1];
    short8_t r;
    r[0] = (short)f2bf(f0.x); r[1] = (short)f2bf(f0.y);
    r[2] = (short)f2bf(f0.z); r[3] = (short)f2bf(f0.w);
    r[4] = (short)f2bf(f1.x); r[5] = (short)f2bf(f1.y);
    r[6] = (short)f2bf(f1.z); r[7] = (short)f2bf(f1.w);
    return r;
}

template <typename TIN, bool SLICED>
__global__ __launch_bounds__(256, 2)
void mfma_dual_gemm(const TIN* __restrict__ in,
                    const float* __restrict__ Wa,
                    const float* __restrict__ Wb,
                    const float* __restrict__ bias,
                    ushort_t* __restrict__ outa,
                    ushort_t* __restrict__ outb) {
    int lane = threadIdx.x & 63;
    int wid  = threadIdx.x >> 6;
    int r16  = lane & 15;
    int g    = lane >> 4;

    short8_t afrag[8][2];
#pragma unroll
    for (int c = 0; c < 8; c++) {
        const float* W = (c < 4) ? Wa : Wb;
        int col = (c & 3) * 16 + r16;
#pragma unroll
        for (int hh = 0; hh < 2; hh++) {
            short8_t a;
#pragma unroll
            for (int j = 0; j < 8; j++)
                a[j] = (short)f2bf(W[(size_t)(32 * hh + 8 * g + j) * CH + col]);
            afrag[c][hh] = a;
        }
    }
    f32x4 binit[8];
#pragma unroll
    for (int c = 0; c < 8; c++) {
#pragma unroll
        for (int rr = 0; rr < 4; rr++)
            binit[c][rr] = (c >= 4 && bias) ? bias[(c & 3) * 16 + g * 4 + rr] : 0.0f;
    }

    const int NT = N_NODES / 16;     // 6250
    for (int t = blockIdx.x * 4 + wid; t < NT; t += gridDim.x * 4) {
        int n = t * 16 + r16;
        short8_t b0, b1;
        if constexpr (SLICED) {
            // k = 8g..8g+8 -> slice g>>1, q g&1 ; k = 32+8g -> slice 2+(g>>1)
            const uint4* in4 = (const uint4*)in;
            uint4 u0 = in4[((size_t)(g >> 1) * N_NODES + n) * 2 + (g & 1)];
            uint4 u1 = in4[((size_t)(2 + (g >> 1)) * N_NODES + n) * 2 + (g & 1)];
            b0 = *(const short8_t*)&u0;
            b1 = *(const short8_t*)&u1;
        } else {
            size_t rowoff = (size_t)n * CH;
            b0 = bfrag_f32(in, rowoff + 8 * g);
            b1 = bfrag_f32(in, rowoff + 32 + 8 * g);
        }
#pragma unroll
        for (int c = 0; c < 8; c++) {
            f32x4 acc = __builtin_amdgcn_mfma_f32_16x16x32_bf16(
                            afrag[c][0], b0, binit[c], 0, 0, 0);
            acc = __builtin_amdgcn_mfma_f32_16x16x32_bf16(
                            afrag[c][1], b1, acc, 0, 0, 0);
            ushort_t* outp = (c < 4) ? outa : outb;
            short4_t o;
            o[0] = (short)f2bf(acc[0]); o[1] = (short)f2bf(acc[1]);
            o[2] = (short)f2bf(acc[2]); o[3] = (short)f2bf(acc[3]);
            // out ch = (c&3)*16 + 4g + r -> slice c&3, q = g>>1, j = 4(g&1)+r
            size_t si = ((size_t)(c & 3) * N_NODES + n) * 16 + (g >> 1) * 8 + (g & 1) * 4;
            *(short4_t*)(outp + si) = o;
        }
    }
}

// ---------------------------------------------------------------------------
// Gather-mean + combine (in-place, slice-major bf16):
//   h[sl][n] = act( mean_{s in N(n)} xl[sl][s] + h[sl][n] )
// One THREAD per (node, slice); slice = bid&3 -> per-XCD L2-resident source.
// No cross-lane ops at all.
// ---------------------------------------------------------------------------
__device__ __forceinline__ void acc8(float2* a, uint4 v) {
    a[0] += make_float2(asf(v.x << 16), asf(v.x & 0xffff0000u));
    a[1] += make_float2(asf(v.y << 16), asf(v.y & 0xffff0000u));
    a[2] += make_float2(asf(v.z << 16), asf(v.z & 0xffff0000u));
    a[3] += make_float2(asf(v.w << 16), asf(v.w & 0xffff0000u));
}

template <bool RELU>
__device__ __forceinline__ uint4 combine8(uint4 rv, const float2* a, float invc) {
    float f0 = asf(rv.x << 16)         + a[0].x * invc;
    float f1 = asf(rv.x & 0xffff0000u) + a[0].y * invc;
    float f2 = asf(rv.y << 16)         + a[1].x * invc;
    float f3 = asf(rv.y & 0xffff0000u) + a[1].y * invc;
    float f4 = asf(rv.z << 16)         + a[2].x * invc;
    float f5 = asf(rv.z & 0xffff0000u) + a[2].y * invc;
    float f6 = asf(rv.w << 16)         + a[3].x * invc;
    float f7 = asf(rv.w & 0xffff0000u) + a[3].y * invc;
    if (RELU) {
        f0 = fmaxf(f0, 0.f); f1 = fmaxf(f1, 0.f);
        f2 = fmaxf(f2, 0.f); f3 = fmaxf(f3, 0.f);
        f4 = fmaxf(f4, 0.f); f5 = fmaxf(f5, 0.f);
        f6 = fmaxf(f6, 0.f); f7 = fmaxf(f7, 0.f);
    }
    return make_uint4(pack2(f0, f1), pack2(f2, f3), pack2(f4, f5), pack2(f6, f7));
}

template <bool RELU>
__global__ __launch_bounds__(256) void gather_mean(const ushort_t* __restrict__ xl,
                                                   const int* __restrict__ row_start,
                                                   const int* __restrict__ csr,
                                                   ushort_t* __restrict__ h) {
    int sl = blockIdx.x & 3;
    int n  = (blockIdx.x >> 2) * 256 + threadIdx.x;
    if (n >= N_NODES) return;
    int beg = row_start[n];
    int deg = row_start[n + 1] - beg;

    float2 a[8];
#pragma unroll
    for (int j = 0; j < 8; j++) a[j] = make_float2(0.f, 0.f);

    const uint4* x4 = (const uint4*)xl;
    size_t sb = (size_t)sl * N_NODES * 2;
    int it = 0;
    for (; it + 1 < deg; it += 2) {            // 2 rows (4 loads) in flight
        int s0 = csr[beg + it];
        int s1 = csr[beg + it + 1];
        uint4 v00 = x4[sb + (size_t)s0 * 2];
        uint4 v01 = x4[sb + (size_t)s0 * 2 + 1];
        uint4 v10 = x4[sb + (size_t)s1 * 2];
        uint4 v11 = x4[sb + (size_t)s1 * 2 + 1];
        acc8(a, v00); acc8(a + 4, v01);
        acc8(a, v10); acc8(a + 4, v11);
    }
    if (it < deg) {
        int s0 = csr[beg + it];
        uint4 v00 = x4[sb + (size_t)s0 * 2];
        uint4 v01 = x4[sb + (size_t)s0 * 2 + 1];
        acc8(a, v00); acc8(a + 4, v01);
    }

    float invc = 1.0f / fmaxf((float)deg, 1.0f);
    uint4* hp = (uint4*)h + sb + (size_t)n * 2;
    uint4 r0 = hp[0];
    uint4 r1 = hp[1];
    hp[0] = combine8<RELU>(r0, a, invc);
    hp[1] = combine8<RELU>(r1, a + 4, invc);
}

// ---------------------------------------------------------------------------
// Pair predictor (slice-major u,v): out[q] = sigmoid(relu(u[a]+v[b])·wp2+bp2)
// ---------------------------------------------------------------------------
__global__ void pair_pred(const ushort_t* __restrict__ u,
                          const ushort_t* __restrict__ v,
                          const int* __restrict__ pa,
                          const int* __restrict__ pb,
                          const float* __restrict__ wp2,
                          const float* __restrict__ bp2,
                          float* __restrict__ out) {
    int tid = threadIdx.x;
    int q   = blockIdx.x * 8 + (tid >> 5);
    int hl  = tid & 31;                        // channel pair 2hl,2hl+1
    if (q >= N_PAIRS) return;
    int a = pa[q], b = pb[q];
    const uint_t* u32 = (const uint_t*)u;
    const uint_t* v32 = (const uint_t*)v;
    size_t sa = ((size_t)(hl >> 3) * N_NODES + a) * 8 + (hl & 7);
    size_t sbv = ((size_t)(hl >> 3) * N_NODES + b) * 8 + (hl & 7);
    uint_t uu = u32[sa];
    uint_t vv = v32[sbv];
    float2 w2 = ((const float2*)wp2)[hl];
    float z0 = fmaxf(asf(uu << 16) + asf(vv << 16), 0.f);
    float z1 = fmaxf(asf(uu & 0xffff0000u) + asf(vv & 0xffff0000u), 0.f);
    float t = z0 * w2.x + z1 * w2.y;
#pragma unroll
    for (int off = 1; off <= 16; off <<= 1) t += __shfl_xor(t, off);
    if (hl == 0) out[q] = 1.0f / (1.0f + expf(-(t + bp2[0])));
}

// ---------------------------------------------------------------------------
extern "C" void kernel_launch(void* const* d_in, const int* in_sizes, int n_in,
                              void* d_out, int out_size, void* d_ws, size_t ws_size,
                              hipStream_t stream) {
    const float* x   = (const float*)d_in[0];
    const int*   ei  = (const int*)d_in[1];   // [2, E]
    const int*   ep  = (const int*)d_in[2];   // [2, P]
    const float* W1l = (const float*)d_in[3];
    const float* W1r = (const float*)d_in[4];
    const float* b1  = (const float*)d_in[5];
    const float* W2l = (const float*)d_in[6];
    const float* W2r = (const float*)d_in[7];
    const float* b2  = (const float*)d_in[8];
    const float* Wp1 = (const float*)d_in[9];
    const float* bp1 = (const float*)d_in[10];
    const float* Wp2 = (const float*)d_in[11];
    const float* bp2 = (const float*)d_in[12];
    float* out = (float*)d_out;

    const int* e_src = ei;
    const int* e_dst = ei + N_EDGES;
    const int* p_a   = ep;
    const int* p_b   = ep + N_PAIRS;

    // workspace layout (4B word units)
    int* gcur      = (int*)d_ws;                            // 256 (pad)
    int* row_start = gcur + 256;                            // N+1 (pad 100608)
    int* csr       = row_start + 100608;                    // E
    uint_t* rec    = (uint_t*)(csr + N_EDGES);              // PB*PCAP
    ushort_t* B1   = (ushort_t*)(rec + (size_t)PB * PCAP);  // N*CH bf16 sliced
    ushort_t* B2   = B1 + (size_t)N_NODES * CH;             // N*CH bf16 sliced

    // ---- CSR build: bucket by dst, per-bucket counting sort ----
    hipMemsetAsync(gcur, 0, PB * sizeof(int), stream);
    k_bucketA<<<512, 256, 0, stream>>>(e_src, e_dst, gcur, rec);
    k_sortplace<<<PB, 256, 0, stream>>>(rec, gcur, row_start, csr);

    const int gmean_blocks = ((N_NODES + 255) / 256) * 4;   // 391*4 = 1564
    const int pair_blocks  = (N_PAIRS + 7) / 8;
    const int gemm_blocks  = 782;

    // ---- layer 1: B1 = x@W1l ; B2 = x@W1r + b1 ; B2 = relu(mean(B1)+B2) ----
    mfma_dual_gemm<float, false><<<gemm_blocks, 256, 0, stream>>>(x, W1l, W1r, b1, B1, B2);
    gather_mean<true><<<gmean_blocks, 256, 0, stream>>>(B1, row_start, csr, B2);

    // ---- layer 2 (in-place): B1 = h1@W2l ; B2 = h1@W2r + b2 ; combine ----
    mfma_dual_gemm<ushort_t, true><<<gemm_blocks, 256, 0, stream>>>(B2, W2l, W2r, b2, B1, B2);
    gather_mean<false><<<gmean_blocks, 256, 0, stream>>>(B1, row_start, csr, B2);

    // ---- pair precompute: B1 = h2@Wp1[64:] (v) ; B2 = h2@Wp1[:64]+bp1 (u) ----
    mfma_dual_gemm<ushort_t, true><<<gemm_blocks, 256, 0, stream>>>(B2, Wp1 + CH * CH, Wp1, bp1, B1, B2);

    // ---- link predictor ----
    pair_pred<<<pair_blocks, 256, 0, stream>>>(B2, B1, p_a, p_b, Wp2, bp2, out);
}

// Round 13
// 184.214 us; speedup vs baseline: 1.3892x; 1.3892x over previous
//
#include <hip/hip_runtime.h>
#include <math.h>

#define N_NODES 100000
#define CH 64
#define N_EDGES 1600000
#define N_PAIRS 200000

#define PB    196            // buckets of 512 dst nodes (196*512 = 100352)
#define PCAP  9216           // slots per bucket (mean 8163, ~11 sigma)

typedef unsigned short ushort_t;
typedef unsigned int   uint_t;
typedef __attribute__((ext_vector_type(8))) short short8_t;   // 8 bf16
typedef __attribute__((ext_vector_type(4))) short short4_t;   // 4 bf16 = 8B
typedef __attribute__((ext_vector_type(4))) float f32x4;      // MFMA acc

// ---- bf16 helpers ----------------------------------------------------------
__device__ __forceinline__ float asf(uint_t u) {
    union { uint_t u; float f; } c; c.u = u; return c.f;
}
__device__ __forceinline__ uint_t f2bf(float f) {
    union { float f; uint_t u; } c; c.f = f;
    return (c.u + 0x7FFFu + ((c.u >> 16) & 1u)) >> 16;
}
__device__ __forceinline__ uint_t pack2(float lo, float hi) {
    return f2bf(lo) | (f2bf(hi) << 16);
}

// ---------------------------------------------------------------------------
// Pass A: bucket edges by dst>>9. Packed record: src<<9 | (dst & 511).
// int4-vectorized edge reads.
// ---------------------------------------------------------------------------
__global__ void k_bucketA(const int* __restrict__ src, const int* __restrict__ dst,
                          int* __restrict__ gcur, uint_t* __restrict__ rec) {
    __shared__ int hist[PB];
    __shared__ int cur[PB];
    int tid = threadIdx.x;              // 256
    if (tid < PB) hist[tid] = 0;
    __syncthreads();
    const int NQ = N_EDGES / 4;         // 400000 int4 quads
    int per = (NQ + gridDim.x - 1) / gridDim.x;
    int q0 = blockIdx.x * per;
    int q1 = min(q0 + per, NQ);
    const int4* dst4 = (const int4*)dst;
    const int4* src4 = (const int4*)src;
    for (int qd = q0 + tid; qd < q1; qd += 256) {
        int4 d = dst4[qd];
        atomicAdd(&hist[d.x >> 9], 1);
        atomicAdd(&hist[d.y >> 9], 1);
        atomicAdd(&hist[d.z >> 9], 1);
        atomicAdd(&hist[d.w >> 9], 1);
    }
    __syncthreads();
    if (tid < PB) cur[tid] = atomicAdd(&gcur[tid], hist[tid]);
    __syncthreads();
    for (int qd = q0 + tid; qd < q1; qd += 256) {
        int4 d = dst4[qd];
        int4 s = src4[qd];
        int b, pos;
        b = d.x >> 9; pos = atomicAdd(&cur[b], 1);
        rec[(size_t)b * PCAP + pos] = ((uint_t)s.x << 9) | (uint_t)(d.x & 511);
        b = d.y >> 9; pos = atomicAdd(&cur[b], 1);
        rec[(size_t)b * PCAP + pos] = ((uint_t)s.y << 9) | (uint_t)(d.y & 511);
        b = d.z >> 9; pos = atomicAdd(&cur[b], 1);
        rec[(size_t)b * PCAP + pos] = ((uint_t)s.z << 9) | (uint_t)(d.z & 511);
        b = d.w >> 9; pos = atomicAdd(&cur[b], 1);
        rec[(size_t)b * PCAP + pos] = ((uint_t)s.w << 9) | (uint_t)(d.w & 511);
    }
}

// ---------------------------------------------------------------------------
// Pass B (fused): per-bucket 512-bin counting sort -> row_start + sorted csr.
// ---------------------------------------------------------------------------
__global__ __launch_bounds__(256) void k_sortplace(const uint_t* __restrict__ rec,
                                                   const int* __restrict__ gcur,
                                                   int* __restrict__ row_start,
                                                   int* __restrict__ csr) {
    __shared__ uint_t ebuf[PCAP];       // 36 KB
    __shared__ int sc[256];
    __shared__ int hist[512];
    __shared__ int offx[512];
    __shared__ int cur[512];
    int b = blockIdx.x, tid = threadIdx.x;

    // bucket base = exclusive prefix of gcur
    sc[tid] = (tid < PB) ? gcur[tid] : 0;
    __syncthreads();
    for (int off = 1; off < 256; off <<= 1) {
        int v = (tid >= off) ? sc[tid - off] : 0;
        __syncthreads();
        sc[tid] += v;
        __syncthreads();
    }
    int base = (b == 0) ? 0 : sc[b - 1];
    int len  = gcur[b];
    __syncthreads();

    // stage + 512-bin histogram
    for (int i = tid; i < 512; i += 256) hist[i] = 0;
    __syncthreads();
    const uint_t* r = rec + (size_t)b * PCAP;
    for (int e = tid; e < len; e += 256) {
        uint_t pk = r[e];
        ebuf[e] = pk;
        atomicAdd(&hist[pk & 511u], 1);
    }
    __syncthreads();

    // exclusive scan of 512 bins
    int p0 = hist[2 * tid], p1 = hist[2 * tid + 1];
    sc[tid] = p0 + p1;
    __syncthreads();
    for (int off = 1; off < 256; off <<= 1) {
        int v = (tid >= off) ? sc[tid - off] : 0;
        __syncthreads();
        sc[tid] += v;
        __syncthreads();
    }
    int exclp = sc[tid] - (p0 + p1);
    offx[2 * tid] = exclp;
    offx[2 * tid + 1] = exclp + p0;
    cur[2 * tid] = exclp;
    cur[2 * tid + 1] = exclp + p0;
    __syncthreads();

    // row_start
    int n0 = b * 512;
    for (int j = tid; j < 512; j += 256) {
        int gn = n0 + j;
        if (gn < N_NODES) row_start[gn] = base + offx[j];
    }
    if (b == PB - 1 && tid == 0) row_start[N_NODES] = N_EDGES;

    // scatter sorted
    for (int e = tid; e < len; e += 256) {
        uint_t pk = ebuf[e];
        int pos = atomicAdd(&cur[pk & 511u], 1);
        csr[base + pos] = (int)(pk >> 9);
    }
}

// ---------------------------------------------------------------------------
// MFMA dual GEMM: outa = in@Wa ; outb = in@Wb + bias  (bf16 out, fp32 acc)
// ---------------------------------------------------------------------------
__device__ __forceinline__ short8_t load_bfrag(const ushort_t* in, size_t off) {
    return *(const short8_t*)(in + off);
}
__device__ __forceinline__ short8_t load_bfrag(const float* in, size_t off) {
    float4 f0 = ((const float4*)(in + off))[0];
    float4 f1 = ((const float4*)(in + off))[1];
    short8_t r;
    r[0] = (short)f2bf(f0.x); r[1] = (short)f2bf(f0.y);
    r[2] = (short)f2bf(f0.z); r[3] = (short)f2bf(f0.w);
    r[4] = (short)f2bf(f1.x); r[5] = (short)f2bf(f1.y);
    r[6] = (short)f2bf(f1.z); r[7] = (short)f2bf(f1.w);
    return r;
}

template <typename TIN>
__global__ __launch_bounds__(256, 2)
void mfma_dual_gemm(const TIN* __restrict__ in,
                    const float* __restrict__ Wa,
                    const float* __restrict__ Wb,
                    const float* __restrict__ bias,
                    ushort_t* __restrict__ outa,
                    ushort_t* __restrict__ outb) {
    int lane = threadIdx.x & 63;
    int wid  = threadIdx.x >> 6;
    int r16  = lane & 15;
    int g    = lane >> 4;

    short8_t afrag[8][2];
#pragma unroll
    for (int c = 0; c < 8; c++) {
        const float* W = (c < 4) ? Wa : Wb;
        int col = (c & 3) * 16 + r16;
#pragma unroll
        for (int hh = 0; hh < 2; hh++) {
            short8_t a;
#pragma unroll
            for (int j = 0; j < 8; j++)
                a[j] = (short)f2bf(W[(size_t)(32 * hh + 8 * g + j) * CH + col]);
            afrag[c][hh] = a;
        }
    }
    f32x4 binit[8];
#pragma unroll
    for (int c = 0; c < 8; c++) {
#pragma unroll
        for (int rr = 0; rr < 4; rr++)
            binit[c][rr] = (c >= 4 && bias) ? bias[(c & 3) * 16 + g * 4 + rr] : 0.0f;
    }

    const int NT = N_NODES / 16;     // 6250
    for (int t = blockIdx.x * 4 + wid; t < NT; t += gridDim.x * 4) {
        int n = t * 16 + r16;
        size_t rowoff = (size_t)n * CH;
        short8_t b0 = load_bfrag(in, rowoff + 8 * g);
        short8_t b1 = load_bfrag(in, rowoff + 32 + 8 * g);
#pragma unroll
        for (int c = 0; c < 8; c++) {
            f32x4 acc = __builtin_amdgcn_mfma_f32_16x16x32_bf16(
                            afrag[c][0], b0, binit[c], 0, 0, 0);
            acc = __builtin_amdgcn_mfma_f32_16x16x32_bf16(
                            afrag[c][1], b1, acc, 0, 0, 0);
            ushort_t* outp = (c < 4) ? outa : outb;
            short4_t o;
            o[0] = (short)f2bf(acc[0]); o[1] = (short)f2bf(acc[1]);
            o[2] = (short)f2bf(acc[2]); o[3] = (short)f2bf(acc[3]);
            *(short4_t*)(outp + rowoff + (c & 3) * 16 + g * 4) = o;
        }
    }
}

// ---------------------------------------------------------------------------
// Gather-mean + combine (in-place, bf16):
//   h[n] = act( mean_{s in N(n)} xl[s] + h[n] )
// One wave = 8 nodes; each 8-lane group owns one node (lane = 16B chunk).
// No cross-lane ops; csr reads are 8-lane broadcasts. 4 rows in flight.
// ---------------------------------------------------------------------------
__device__ __forceinline__ void acc8(float2* a, uint4 v) {
    a[0] += make_float2(asf(v.x << 16), asf(v.x & 0xffff0000u));
    a[1] += make_float2(asf(v.y << 16), asf(v.y & 0xffff0000u));
    a[2] += make_float2(asf(v.z << 16), asf(v.z & 0xffff0000u));
    a[3] += make_float2(asf(v.w << 16), asf(v.w & 0xffff0000u));
}

template <bool RELU>
__global__ void gather_mean(const ushort_t* __restrict__ xl,
                            const int* __restrict__ row_start,
                            const int* __restrict__ csr,
                            ushort_t* __restrict__ h) {
    int tid  = threadIdx.x;
    int wave = tid >> 6;
    int lane = tid & 63;
    int grp  = lane >> 3;      // node slot 0..7 within wave
    int c8   = lane & 7;       // 16B channel chunk

    int n = (blockIdx.x * 4 + wave) * 8 + grp;    // exact cover, no tail
    int beg = row_start[n];
    int deg = row_start[n + 1] - beg;             // group-uniform

    float2 a[4];
#pragma unroll
    for (int j = 0; j < 4; j++) a[j] = make_float2(0.f, 0.f);

    const uint4* xl4 = (const uint4*)xl;
    int it = 0;
    for (; it + 3 < deg; it += 4) {               // 4 rows in flight
        int s0 = csr[beg + it];                   // 8-lane broadcast loads
        int s1 = csr[beg + it + 1];
        int s2 = csr[beg + it + 2];
        int s3 = csr[beg + it + 3];
        uint4 v0 = xl4[(size_t)s0 * 8 + c8];
        uint4 v1 = xl4[(size_t)s1 * 8 + c8];
        uint4 v2 = xl4[(size_t)s2 * 8 + c8];
        uint4 v3 = xl4[(size_t)s3 * 8 + c8];
        acc8(a, v0);
        acc8(a, v1);
        acc8(a, v2);
        acc8(a, v3);
    }
    for (; it < deg; ++it) {
        int s0 = csr[beg + it];
        uint4 v0 = xl4[(size_t)s0 * 8 + c8];
        acc8(a, v0);
    }

    float invc = 1.0f / fmaxf((float)deg, 1.0f);
    uint4* hp = (uint4*)(h + (size_t)n * CH) + c8;
    uint4 rv = *hp;
    float f0 = asf(rv.x << 16)          + a[0].x * invc;
    float f1 = asf(rv.x & 0xffff0000u)  + a[0].y * invc;
    float f2 = asf(rv.y << 16)          + a[1].x * invc;
    float f3 = asf(rv.y & 0xffff0000u)  + a[1].y * invc;
    float f4 = asf(rv.z << 16)          + a[2].x * invc;
    float f5 = asf(rv.z & 0xffff0000u)  + a[2].y * invc;
    float f6 = asf(rv.w << 16)          + a[3].x * invc;
    float f7 = asf(rv.w & 0xffff0000u)  + a[3].y * invc;
    if (RELU) {
        f0 = fmaxf(f0, 0.f); f1 = fmaxf(f1, 0.f);
        f2 = fmaxf(f2, 0.f); f3 = fmaxf(f3, 0.f);
        f4 = fmaxf(f4, 0.f); f5 = fmaxf(f5, 0.f);
        f6 = fmaxf(f6, 0.f); f7 = fmaxf(f7, 0.f);
    }
    *hp = make_uint4(pack2(f0, f1), pack2(f2, f3), pack2(f4, f5), pack2(f6, f7));
}

// ---------------------------------------------------------------------------
// Pair predictor: out[q] = sigmoid( relu(u[a] + v[b]) · wp2 + bp2 )
// ---------------------------------------------------------------------------
__global__ void pair_pred(const ushort_t* __restrict__ u,
                          const ushort_t* __restrict__ v,
                          const int* __restrict__ pa,
                          const int* __restrict__ pb,
                          const float* __restrict__ wp2,
                          const float* __restrict__ bp2,
                          float* __restrict__ out) {
    int tid = threadIdx.x;
    int q   = blockIdx.x * 8 + (tid >> 5);
    int hl  = tid & 31;
    if (q >= N_PAIRS) return;
    int a = pa[q], b = pb[q];
    uint_t uu = ((const uint_t*)u)[(size_t)a * 32 + hl];
    uint_t vv = ((const uint_t*)v)[(size_t)b * 32 + hl];
    float2 w2 = ((const float2*)wp2)[hl];
    float z0 = fmaxf(asf(uu << 16) + asf(vv << 16), 0.f);
    float z1 = fmaxf(asf(uu & 0xffff0000u) + asf(vv & 0xffff0000u), 0.f);
    float t = z0 * w2.x + z1 * w2.y;
#pragma unroll
    for (int off = 1; off <= 16; off <<= 1) t += __shfl_xor(t, off);
    if (hl == 0) out[q] = 1.0f / (1.0f + expf(-(t + bp2[0])));
}

// ---------------------------------------------------------------------------
extern "C" void kernel_launch(void* const* d_in, const int* in_sizes, int n_in,
                              void* d_out, int out_size, void* d_ws, size_t ws_size,
                              hipStream_t stream) {
    const float* x   = (const float*)d_in[0];
    const int*   ei  = (const int*)d_in[1];   // [2, E]
    const int*   ep  = (const int*)d_in[2];   // [2, P]
    const float* W1l = (const float*)d_in[3];
    const float* W1r = (const float*)d_in[4];
    const float* b1  = (const float*)d_in[5];
    const float* W2l = (const float*)d_in[6];
    const float* W2r = (const float*)d_in[7];
    const float* b2  = (const float*)d_in[8];
    const float* Wp1 = (const float*)d_in[9];
    const float* bp1 = (const float*)d_in[10];
    const float* Wp2 = (const float*)d_in[11];
    const float* bp2 = (const float*)d_in[12];
    float* out = (float*)d_out;

    const int* e_src = ei;
    const int* e_dst = ei + N_EDGES;
    const int* p_a   = ep;
    const int* p_b   = ep + N_PAIRS;

    // workspace layout (4B word units)
    int* gcur      = (int*)d_ws;                            // 256 (pad)
    int* row_start = gcur + 256;                            // N+1 (pad 100608)
    int* csr       = row_start + 100608;                    // E
    uint_t* rec    = (uint_t*)(csr + N_EDGES);              // PB*PCAP
    ushort_t* B1   = (ushort_t*)(rec + (size_t)PB * PCAP);  // N*CH bf16
    ushort_t* B2   = B1 + (size_t)N_NODES * CH;             // N*CH bf16

    // ---- CSR build: bucket by dst, per-bucket counting sort ----
    hipMemsetAsync(gcur, 0, PB * sizeof(int), stream);
    k_bucketA<<<512, 256, 0, stream>>>(e_src, e_dst, gcur, rec);
    k_sortplace<<<PB, 256, 0, stream>>>(rec, gcur, row_start, csr);

    const int gmean_blocks = N_NODES / 32;    // 3125, exact
    const int pair_blocks  = (N_PAIRS + 7) / 8;
    const int gemm_blocks  = 782;

    // ---- layer 1: B1 = x@W1l ; B2 = x@W1r + b1 ; B2 = relu(mean(B1)+B2) ----
    mfma_dual_gemm<float><<<gemm_blocks, 256, 0, stream>>>(x, W1l, W1r, b1, B1, B2);
    gather_mean<true><<<gmean_blocks, 256, 0, stream>>>(B1, row_start, csr, B2);

    // ---- layer 2 (in-place): B1 = h1@W2l ; B2 = h1@W2r + b2 ; combine ----
    mfma_dual_gemm<ushort_t><<<gemm_blocks, 256, 0, stream>>>(B2, W2l, W2r, b2, B1, B2);
    gather_mean<false><<<gmean_blocks, 256, 0, stream>>>(B1, row_start, csr, B2);

    // ---- pair precompute: B1 = h2@Wp1[64:] (v) ; B2 = h2@Wp1[:64]+bp1 (u) ----
    mfma_dual_gemm<ushort_t><<<gemm_blocks, 256, 0, stream>>>(B2, Wp1 + CH * CH, Wp1, bp1, B1, B2);

    // ---- link predictor ----
    pair_pred<<<pair_blocks, 256, 0, stream>>>(B2, B1, p_a, p_b, Wp2, bp2, out);
}